// Round 3
// baseline (210.387 us; speedup 1.0000x reference)
//
#include <hip/hip_runtime.h>
#include <hip/hip_bf16.h>

// Problem constants: B=8, N=128, D=512, L=48, 2 GCN layers.
//   t = einsum('ldk,bjk->bljd', w, h)  ==  T[(b*128+j), l*512+d] = sum_k H[bj,k]*Wflat[ld,k]
//   msg[b,i,d] = sum_j adj[b,i,j] * T[b*128+j, lab[b,i,j]*512+d];  h = relu(msg/(1+deg))
//   out = relu(relu(h@w0^T+b0)@w1^T+b1)

typedef unsigned short u16;
typedef unsigned int u32;
using bf16x8 = __bf16 __attribute__((ext_vector_type(8)));
using f32x4 = float __attribute__((ext_vector_type(4)));

__device__ __forceinline__ u16 f2bf(float f) {
  u32 u = __float_as_uint(f);
  u32 r = u + 0x7fffu + ((u >> 16) & 1u);   // round-to-nearest-even
  return (u16)(r >> 16);
}
__device__ __forceinline__ float bf2f(u16 h) {
  return __uint_as_float(((u32)h) << 16);
}

// ---------------- fp32 -> bf16 conversion (float4 vectorized) ----------------
__global__ __launch_bounds__(256)
void cvt_f32_bf16(const float* __restrict__ in, u16* __restrict__ out, int n4) {
  int stride = gridDim.x * blockDim.x;
  for (int i = blockIdx.x * blockDim.x + threadIdx.x; i < n4; i += stride) {
    float4 v = ((const float4*)in)[i];
    uint2 o;
    o.x = (u32)f2bf(v.x) | ((u32)f2bf(v.y) << 16);
    o.y = (u32)f2bf(v.z) | ((u32)f2bf(v.w) << 16);
    ((uint2*)out)[i] = o;
  }
}

// ---------------- bf16 NT GEMM: C[m,n] = sum_k A[m,k]*B[n,k] ----------------
// A: MxK row-major bf16, B: NxK row-major bf16, C: MxN row-major bf16.
// 128x128 tile, BK=32, 256 threads (4 waves, 2x2), 16x16x32 MFMA, 4x4 frags/wave.
#define BM 128
#define BN 128
#define BK 32

__device__ __forceinline__ void gl_lds16(const u16* g, u16* l) {
  __builtin_amdgcn_global_load_lds(
      (const __attribute__((address_space(1))) u32*)g,
      (__attribute__((address_space(3))) u32*)l, 16, 0, 0);
}

__global__ __launch_bounds__(256)
void gemm_nt_bf16(const u16* __restrict__ A, const u16* __restrict__ B,
                  u16* __restrict__ C, int M, int N, int K) {
  __shared__ u16 sA[2][BM * BK];   // 8 KB per buffer
  __shared__ u16 sB[2][BN * BK];
  const int tid = threadIdx.x;
  const int lane = tid & 63;
  const int wid = tid >> 6;
  const int wm = wid >> 1;      // 0..1
  const int wn = wid & 1;       // 0..1
  const int m0 = blockIdx.y * BM;
  const int n0 = blockIdx.x * BN;

  // staging: thread tid loads 16B at linear tile offset tid*16 (rows 0..63),
  // plus rows 64..127 at +2048 elems. LDS dest = wave-uniform base + lane*16. 
  const int srow = tid >> 2;          // 0..63
  const int scol = (tid & 3) * 8;     // k-element offset 0,8,16,24
  const u16* gA0 = A + (size_t)(m0 + srow) * K + scol;
  const u16* gA1 = A + (size_t)(m0 + 64 + srow) * K + scol;
  const u16* gB0 = B + (size_t)(n0 + srow) * K + scol;
  const u16* gB1 = B + (size_t)(n0 + 64 + srow) * K + scol;

  auto stage = [&](int buf, int kt) {
    const int ko = kt * BK;
    gl_lds16(gA0 + ko, &sA[buf][tid * 8]);
    gl_lds16(gA1 + ko, &sA[buf][2048 + tid * 8]);
    gl_lds16(gB0 + ko, &sB[buf][tid * 8]);
    gl_lds16(gB1 + ko, &sB[buf][2048 + tid * 8]);
  };

  f32x4 acc[4][4];
#pragma unroll
  for (int i = 0; i < 4; ++i)
#pragma unroll
    for (int j = 0; j < 4; ++j)
      acc[i][j] = (f32x4){0.f, 0.f, 0.f, 0.f};

  const int NT = K / BK;
  stage(0, 0);
  asm volatile("s_waitcnt vmcnt(0)" ::: "memory");
  __syncthreads();

  const int r15 = lane & 15;
  const int ksub = (lane >> 4) * 8;
  int cur = 0;
  for (int kt = 0; kt < NT; ++kt) {
    if (kt + 1 < NT) stage(cur ^ 1, kt + 1);   // prefetch next K-tile (in flight)

    bf16x8 af[4], bfr[4];
#pragma unroll
    for (int mi = 0; mi < 4; ++mi)
      af[mi] = *(const bf16x8*)&sA[cur][(wm * 64 + mi * 16 + r15) * BK + ksub];
#pragma unroll
    for (int ni = 0; ni < 4; ++ni)
      bfr[ni] = *(const bf16x8*)&sB[cur][(wn * 64 + ni * 16 + r15) * BK + ksub];

#pragma unroll
    for (int mi = 0; mi < 4; ++mi)
#pragma unroll
      for (int ni = 0; ni < 4; ++ni)
        acc[mi][ni] = __builtin_amdgcn_mfma_f32_16x16x32_bf16(
            af[mi], bfr[ni], acc[mi][ni], 0, 0, 0);

    asm volatile("s_waitcnt vmcnt(0)" ::: "memory");  // drain prefetch
    __syncthreads();
    cur ^= 1;
  }

  // epilogue: C/D layout col=lane&15, row=(lane>>4)*4+reg  [m89-verified]
  const int rq = (lane >> 4) * 4;
#pragma unroll
  for (int mi = 0; mi < 4; ++mi) {
#pragma unroll
    for (int ni = 0; ni < 4; ++ni) {
      const int row = m0 + wm * 64 + mi * 16 + rq;
      const int col = n0 + wn * 64 + ni * 16 + r15;
      const size_t base = (size_t)row * N + col;
      f32x4 v = acc[mi][ni];
#pragma unroll
      for (int r = 0; r < 4; ++r)
        C[base + (size_t)r * N] = f2bf(v[r]);
    }
  }
}

// ---------------- per-row gather-reduce: msg + relu(msg/denom) -> bf16 -------
// block = (b,i); 256 threads, 2 d-elements each (D=512).
__global__ __launch_bounds__(256)
void gcn_agg(const u16* __restrict__ T, const float* __restrict__ adj,
             const int* __restrict__ lab, u16* __restrict__ Hout) {
  const int bi = blockIdx.x;      // b*128 + i
  const int b = bi >> 7;
  const int tid = threadIdx.x;
  __shared__ float s_adj[128];
  __shared__ int s_off[128];      // precomputed T row offsets (elements)
  if (tid < 128) {
    s_adj[tid] = adj[(size_t)bi * 128 + tid];
    const int lv = lab[(size_t)bi * 128 + tid];
    s_off[tid] = ((b * 128 + tid) * 48 + lv) * 512;
  }
  __syncthreads();

  const int d = tid * 2;
  float den = 1.0f, a0 = 0.f, a1 = 0.f;
#pragma unroll 8
  for (int j = 0; j < 128; ++j) {
    const float a = s_adj[j];       // 0.0 or 1.0 (block-uniform broadcast)
    den += a;
    const u32 u = *(const u32*)&T[(size_t)s_off[j] + d];
    a0 = fmaf(a, __uint_as_float((u & 0xffffu) << 16), a0);
    a1 = fmaf(a, __uint_as_float(u & 0xffff0000u), a1);
  }
  const float r = 1.0f / den;
  a0 = fmaxf(a0 * r, 0.0f);
  a1 = fmaxf(a1 * r, 0.0f);
  const u32 o = (u32)f2bf(a0) | ((u32)f2bf(a1) << 16);
  *(u32*)&Hout[(size_t)bi * 512 + d] = o;
}

// ---------------- fp32 NT GEMM + bias + ReLU (MLP, small) -------------------
// out[m,n] = relu(sum_k A[m,k]*W[n,k] + bias[n]); 64x64 tile, 256 thr, 4x4/thr.
template <bool A_BF16>
__global__ __launch_bounds__(256)
void mlp_gemm(const void* __restrict__ Ain, const float* __restrict__ W,
              const float* __restrict__ bias, float* __restrict__ out,
              int M, int N, int K) {
  const int tid = threadIdx.x;
  const int tx = tid & 15;
  const int ty = tid >> 4;
  const int n0 = blockIdx.x * 64;
  const int m0 = blockIdx.y * 64;
  __shared__ float sA[64][17];
  __shared__ float sB[64][17];
  float acc[4][4] = {};

  for (int k0 = 0; k0 < K; k0 += 16) {
#pragma unroll
    for (int i = 0; i < 4; ++i) {
      const int idx = tid + i * 256;
      const int rr = idx >> 4;
      const int cc = idx & 15;
      float av;
      if (A_BF16)
        av = bf2f(((const u16*)Ain)[(size_t)(m0 + rr) * K + k0 + cc]);
      else
        av = ((const float*)Ain)[(size_t)(m0 + rr) * K + k0 + cc];
      sA[rr][cc] = av;
      sB[rr][cc] = W[(size_t)(n0 + rr) * K + k0 + cc];
    }
    __syncthreads();
#pragma unroll
    for (int k = 0; k < 16; ++k) {
      float ar[4], bc[4];
#pragma unroll
      for (int r = 0; r < 4; ++r) ar[r] = sA[ty * 4 + r][k];
#pragma unroll
      for (int c = 0; c < 4; ++c) bc[c] = sB[tx * 4 + c][k];
#pragma unroll
      for (int r = 0; r < 4; ++r)
#pragma unroll
        for (int c = 0; c < 4; ++c)
          acc[r][c] = fmaf(ar[r], bc[c], acc[r][c]);
    }
    __syncthreads();
  }
#pragma unroll
  for (int r = 0; r < 4; ++r) {
#pragma unroll
    for (int c = 0; c < 4; ++c) {
      const int row = m0 + ty * 4 + r;
      const int col = n0 + tx * 4 + c;
      out[(size_t)row * N + col] = fmaxf(acc[r][c] + bias[col], 0.0f);
    }
  }
}

// ---------------------------------------------------------------------------
extern "C" void kernel_launch(void* const* d_in, const int* in_sizes, int n_in,
                              void* d_out, int out_size, void* d_ws, size_t ws_size,
                              hipStream_t stream) {
  const float* gcn_inputs = (const float*)d_in[0];
  // d_in[1] = word_seq_len: unused by the reference
  const float* adj = (const float*)d_in[2];
  const int* lab = (const int*)d_in[3];
  const float* w_params = (const float*)d_in[4];
  const float* w0 = (const float*)d_in[5];
  const float* b0 = (const float*)d_in[6];
  const float* w1 = (const float*)d_in[7];
  const float* b1 = (const float*)d_in[8];
  float* out = (float*)d_out;

  // workspace layout (bytes, all 16B-aligned):
  //   Wbf  [0,            25165824)  : 48*512*512 bf16
  //   T    [25165824,     75497472)  : 1024 x 24576 bf16
  //   Ha   [75497472,     76546048)  : 1024 x 512 bf16
  //   Hb   [76546048,     77594624)  : 1024 x 512 bf16
  //   X1   [77594624,     79691776)  : 1024 x 512 f32
  char* ws = (char*)d_ws;
  u16* Wbf = (u16*)ws;
  u16* T = (u16*)(ws + 25165824);
  u16* Ha = (u16*)(ws + 75497472);
  u16* Hb = (u16*)(ws + 76546048);
  float* X1 = (float*)(ws + 77594624);

  cvt_f32_bf16<<<2048, 256, 0, stream>>>(w_params, Wbf, (48 * 512 * 512) / 4);
  cvt_f32_bf16<<<512, 256, 0, stream>>>(gcn_inputs, Ha, (8 * 128 * 512) / 4);

  dim3 gg(24576 / BN, 1024 / BM);   // (192, 8)

  // layer 1
  gemm_nt_bf16<<<gg, 256, 0, stream>>>(Ha, Wbf, T, 1024, 24576, 512);
  gcn_agg<<<1024, 256, 0, stream>>>(T, adj, lab, Hb);
  // layer 2
  gemm_nt_bf16<<<gg, 256, 0, stream>>>(Hb, Wbf, T, 1024, 24576, 512);
  gcn_agg<<<1024, 256, 0, stream>>>(T, adj, lab, Ha);

  // MLP (fp32 for accuracy margin)
  dim3 gm(512 / 64, 1024 / 64);     // (8, 16)
  mlp_gemm<true><<<gm, 256, 0, stream>>>(Ha, w0, b0, X1, 1024, 512, 512);
  mlp_gemm<false><<<gm, 256, 0, stream>>>(X1, w1, b1, out, 1024, 512, 512);
}

// Round 4
// 185.158 us; speedup vs baseline: 1.1363x; 1.1363x over previous
//
#include <hip/hip_runtime.h>
#include <hip/hip_bf16.h>

// Problem constants: B=8, N=128, D=512, L=48, 2 GCN layers.
//   t = einsum('ldk,bjk->bljd', w, h)  ==  T[(b*128+j), l*512+d] = sum_k H[bj,k]*Wflat[ld,k]
//   msg[b,i,d] = sum_j adj[b,i,j] * T[b*128+j, lab[b,i,j]*512+d];  h = relu(msg/(1+deg))
//   out = relu(relu(h@w0^T+b0)@w1^T+b1)
// MLP runs on MFMA via bf16 hi/lo compensation (fp32-equivalent accuracy):
//   layer1: A'=[Ha,Ha]        B'=[W0hi,W0lo]       K=1024
//   layer2: A'=[X1hi,X1hi,X1lo] B'=[W1hi,W1lo,W1hi] K=1536   (drop lo*lo ~ 2^-16)

typedef unsigned short u16;
typedef unsigned int u32;
using bf16x8 = __bf16 __attribute__((ext_vector_type(8)));
using f32x4 = float __attribute__((ext_vector_type(4)));

__device__ __forceinline__ u16 f2bf(float f) {
  u32 u = __float_as_uint(f);
  u32 r = u + 0x7fffu + ((u >> 16) & 1u);   // round-to-nearest-even
  return (u16)(r >> 16);
}
__device__ __forceinline__ float bf2f(u16 h) {
  return __uint_as_float(((u32)h) << 16);
}

// ---------------- fp32 -> bf16 conversion (float4 vectorized) ----------------
__global__ __launch_bounds__(256)
void cvt_f32_bf16(const float* __restrict__ in, u16* __restrict__ out, int n4) {
  int stride = gridDim.x * blockDim.x;
  for (int i = blockIdx.x * blockDim.x + threadIdx.x; i < n4; i += stride) {
    float4 v = ((const float4*)in)[i];
    uint2 o;
    o.x = (u32)f2bf(v.x) | ((u32)f2bf(v.y) << 16);
    o.y = (u32)f2bf(v.z) | ((u32)f2bf(v.w) << 16);
    ((uint2*)out)[i] = o;
  }
}

// ---------------- MLP weight prep: hi/lo split into concatenated-K layout ----
// w0 (512x512 f32) -> Bp1 (512x1024 bf16): [n,k]=hi, [n,512+k]=lo
// w1 (512x512 f32) -> Bp2 (512x1536 bf16): [n,k]=hi, [n,512+k]=lo, [n,1024+k]=hi
__global__ __launch_bounds__(256)
void prep_mlp_w(const float* __restrict__ w0, const float* __restrict__ w1,
                u16* __restrict__ Bp1, u16* __restrict__ Bp2) {
  int idx = blockIdx.x * 256 + threadIdx.x;   // grid covers 2*262144
  if (idx < 262144) {
    const int n = idx >> 9, k = idx & 511;
    const float v = w0[idx];
    const u16 hi = f2bf(v);
    const float lo = v - bf2f(hi);
    Bp1[n * 1024 + k] = hi;
    Bp1[n * 1024 + 512 + k] = f2bf(lo);
  } else {
    const int j = idx - 262144;
    const int n = j >> 9, k = j & 511;
    const float v = w1[j];
    const u16 hi = f2bf(v);
    const float lo = v - bf2f(hi);
    Bp2[n * 1536 + k] = hi;
    Bp2[n * 1536 + 512 + k] = f2bf(lo);
    Bp2[n * 1536 + 1024 + k] = hi;
  }
}

// ---------------- bf16 NT GEMM: C[m,n] = sum_k A[m,k]*B[n,k] ----------------
// A: MxK row-major bf16, B: NxK row-major bf16.
// 128x128 tile, BK=32, 256 threads (4 waves, 2x2), 16x16x32 MFMA, 4x4 frags/wave.
// EPI 0: bf16 store (ldc = N of C)
// EPI 1: relu(acc+bias) -> hi/lo split into Ap2 layout (hi@col, hi@512+col, lo@1024+col), ldc=1536
// EPI 2: relu(acc+bias) -> fp32 store, ldc = N of C
#define BM 128
#define BN 128
#define BK 32

__device__ __forceinline__ void gl_lds16(const u16* g, u16* l) {
  __builtin_amdgcn_global_load_lds(
      (const __attribute__((address_space(1))) u32*)g,
      (__attribute__((address_space(3))) u32*)l, 16, 0, 0);
}

template <int EPI>
__global__ __launch_bounds__(256)
void gemm_nt_bf16(const u16* __restrict__ A, const u16* __restrict__ B,
                  void* __restrict__ C, const float* __restrict__ bias,
                  int N, int K, int ldc) {
  __shared__ u16 sA[2][BM * BK];   // 8 KB per buffer
  __shared__ u16 sB[2][BN * BK];
  const int tid = threadIdx.x;
  const int lane = tid & 63;
  const int wid = tid >> 6;
  const int wm = wid >> 1;      // 0..1
  const int wn = wid & 1;       // 0..1
  const int m0 = blockIdx.y * BM;
  const int n0 = blockIdx.x * BN;

  const int srow = tid >> 2;          // 0..63
  const int scol = (tid & 3) * 8;     // k-element offset 0,8,16,24
  const u16* gA0 = A + (size_t)(m0 + srow) * K + scol;
  const u16* gA1 = A + (size_t)(m0 + 64 + srow) * K + scol;
  const u16* gB0 = B + (size_t)(n0 + srow) * K + scol;
  const u16* gB1 = B + (size_t)(n0 + 64 + srow) * K + scol;

  auto stage = [&](int buf, int kt) {
    const int ko = kt * BK;
    gl_lds16(gA0 + ko, &sA[buf][tid * 8]);
    gl_lds16(gA1 + ko, &sA[buf][2048 + tid * 8]);
    gl_lds16(gB0 + ko, &sB[buf][tid * 8]);
    gl_lds16(gB1 + ko, &sB[buf][2048 + tid * 8]);
  };

  f32x4 acc[4][4];
#pragma unroll
  for (int i = 0; i < 4; ++i)
#pragma unroll
    for (int j = 0; j < 4; ++j)
      acc[i][j] = (f32x4){0.f, 0.f, 0.f, 0.f};

  const int NT = K / BK;
  stage(0, 0);
  asm volatile("s_waitcnt vmcnt(0)" ::: "memory");
  __syncthreads();

  const int r15 = lane & 15;
  const int ksub = (lane >> 4) * 8;
  int cur = 0;
  for (int kt = 0; kt < NT; ++kt) {
    if (kt + 1 < NT) stage(cur ^ 1, kt + 1);   // prefetch next K-tile (in flight)

    bf16x8 af[4], bfr[4];
#pragma unroll
    for (int mi = 0; mi < 4; ++mi)
      af[mi] = *(const bf16x8*)&sA[cur][(wm * 64 + mi * 16 + r15) * BK + ksub];
#pragma unroll
    for (int ni = 0; ni < 4; ++ni)
      bfr[ni] = *(const bf16x8*)&sB[cur][(wn * 64 + ni * 16 + r15) * BK + ksub];

#pragma unroll
    for (int mi = 0; mi < 4; ++mi)
#pragma unroll
      for (int ni = 0; ni < 4; ++ni)
        acc[mi][ni] = __builtin_amdgcn_mfma_f32_16x16x32_bf16(
            af[mi], bfr[ni], acc[mi][ni], 0, 0, 0);

    asm volatile("s_waitcnt vmcnt(0)" ::: "memory");  // drain prefetch
    __syncthreads();
    cur ^= 1;
  }

  // epilogue: C/D layout col=lane&15, row=(lane>>4)*4+reg  [m89-verified]
  const int rq = (lane >> 4) * 4;
#pragma unroll
  for (int mi = 0; mi < 4; ++mi) {
#pragma unroll
    for (int ni = 0; ni < 4; ++ni) {
      const int row = m0 + wm * 64 + mi * 16 + rq;
      const int col = n0 + wn * 64 + ni * 16 + r15;
      f32x4 v = acc[mi][ni];
      if (EPI == 0) {
        u16* Cb = (u16*)C;
        const size_t base = (size_t)row * ldc + col;
#pragma unroll
        for (int r = 0; r < 4; ++r)
          Cb[base + (size_t)r * ldc] = f2bf(v[r]);
      } else if (EPI == 1) {
        u16* Cb = (u16*)C;
        const float bv = bias[col];
#pragma unroll
        for (int r = 0; r < 4; ++r) {
          const float x = fmaxf(v[r] + bv, 0.0f);
          const u16 hi = f2bf(x);
          const float lo = x - bf2f(hi);
          const size_t base = (size_t)(row + r) * 1536 + col;
          Cb[base] = hi;
          Cb[base + 512] = hi;
          Cb[base + 1024] = f2bf(lo);
        }
      } else {
        float* Cf = (float*)C;
        const float bv = bias[col];
#pragma unroll
        for (int r = 0; r < 4; ++r)
          Cf[(size_t)(row + r) * ldc + col] = fmaxf(v[r] + bv, 0.0f);
      }
    }
  }
}

// ---------------- per-row gather-reduce: msg + relu(msg/denom) -> bf16 -------
// block = (b,i); 256 threads, 2 d-elements each (D=512).
// DUP: write result twice (row stride 1024) to build the MLP layer-1 A'=[H,H].
template <bool DUP>
__global__ __launch_bounds__(256)
void gcn_agg(const u16* __restrict__ T, const float* __restrict__ adj,
             const int* __restrict__ lab, u16* __restrict__ Hout) {
  const int bi = blockIdx.x;      // b*128 + i
  const int b = bi >> 7;
  const int tid = threadIdx.x;
  __shared__ float s_adj[128];
  __shared__ int s_off[128];      // precomputed T row offsets (elements)
  if (tid < 128) {
    s_adj[tid] = adj[(size_t)bi * 128 + tid];
    const int lv = lab[(size_t)bi * 128 + tid];
    s_off[tid] = ((b * 128 + tid) * 48 + lv) * 512;
  }
  __syncthreads();

  const int d = tid * 2;
  float den = 1.0f, a0 = 0.f, a1 = 0.f;
#pragma unroll 8
  for (int j = 0; j < 128; ++j) {
    const float a = s_adj[j];       // 0.0 or 1.0 (block-uniform broadcast)
    den += a;
    const u32 u = *(const u32*)&T[(size_t)s_off[j] + d];
    a0 = fmaf(a, __uint_as_float((u & 0xffffu) << 16), a0);
    a1 = fmaf(a, __uint_as_float(u & 0xffff0000u), a1);
  }
  const float r = 1.0f / den;
  a0 = fmaxf(a0 * r, 0.0f);
  a1 = fmaxf(a1 * r, 0.0f);
  const u32 o = (u32)f2bf(a0) | ((u32)f2bf(a1) << 16);
  if (DUP) {
    *(u32*)&Hout[(size_t)bi * 1024 + d] = o;
    *(u32*)&Hout[(size_t)bi * 1024 + 512 + d] = o;
  } else {
    *(u32*)&Hout[(size_t)bi * 512 + d] = o;
  }
}

// ---------------------------------------------------------------------------
extern "C" void kernel_launch(void* const* d_in, const int* in_sizes, int n_in,
                              void* d_out, int out_size, void* d_ws, size_t ws_size,
                              hipStream_t stream) {
  const float* gcn_inputs = (const float*)d_in[0];
  // d_in[1] = word_seq_len: unused by the reference
  const float* adj = (const float*)d_in[2];
  const int* lab = (const int*)d_in[3];
  const float* w_params = (const float*)d_in[4];
  const float* w0 = (const float*)d_in[5];
  const float* b0 = (const float*)d_in[6];
  const float* w1 = (const float*)d_in[7];
  const float* b1 = (const float*)d_in[8];
  float* out = (float*)d_out;

  // workspace layout (bytes, all 16B-aligned):
  //   Wbf  [0,        25165824)  : 48*512*512 bf16
  //   T    [25165824, 75497472)  : 1024 x 24576 bf16
  //     Bp1 = T+0      (512x1024 bf16, 1 MB)   } written AFTER last T read
  //     Bp2 = T+1MB    (512x1536 bf16, 1.5 MB) }
  //   Ha   [75497472, +1MB)      : 1024 x 512 bf16
  //   Hb   [76546048, +1MB)      : 1024 x 512 bf16
  //   Ap1  [77594624, +2MB)      : 1024 x 1024 bf16 (agg#2 DUP output)
  //   Ap2  [79691776, +3MB)      : 1024 x 1536 bf16 (MLP1 hi/hi/lo output)
  char* ws = (char*)d_ws;
  u16* Wbf = (u16*)ws;
  u16* T = (u16*)(ws + 25165824);
  u16* Bp1 = T;
  u16* Bp2 = (u16*)(ws + 25165824 + (1 << 20));
  u16* Ha = (u16*)(ws + 75497472);
  u16* Hb = (u16*)(ws + 76546048);
  u16* Ap1 = (u16*)(ws + 77594624);
  u16* Ap2 = (u16*)(ws + 79691776);

  cvt_f32_bf16<<<2048, 256, 0, stream>>>(w_params, Wbf, (48 * 512 * 512) / 4);
  cvt_f32_bf16<<<512, 256, 0, stream>>>(gcn_inputs, Ha, (8 * 128 * 512) / 4);

  dim3 gg(24576 / BN, 1024 / BM);   // (192, 8)

  // GCN layer 1
  gemm_nt_bf16<0><<<gg, 256, 0, stream>>>(Ha, Wbf, T, nullptr, 24576, 512, 24576);
  gcn_agg<false><<<1024, 256, 0, stream>>>(T, adj, lab, Hb);
  // GCN layer 2
  gemm_nt_bf16<0><<<gg, 256, 0, stream>>>(Hb, Wbf, T, nullptr, 24576, 512, 24576);
  gcn_agg<true><<<1024, 256, 0, stream>>>(T, adj, lab, Ap1);   // -> A'=[H,H]

  // MLP weight hi/lo prep (T region is dead now; Bp1/Bp2 alias it)
  prep_mlp_w<<<2048, 256, 0, stream>>>(w0, w1, Bp1, Bp2);

  // MLP layer 1: X1 = relu(Ha@W0^T+b0), emitted as [X1hi, X1hi, X1lo] (K'=1536)
  dim3 gm(512 / BN, 1024 / BM);     // (4, 8)
  gemm_nt_bf16<1><<<gm, 256, 0, stream>>>(Ap1, Bp1, Ap2, b0, 512, 1024, 1536);
  // MLP layer 2: out = relu(X1@W1^T+b1), fp32
  gemm_nt_bf16<2><<<gm, 256, 0, stream>>>(Ap2, Bp2, out, b1, 512, 1536, 512);
}